// Round 11
// baseline (435.488 us; speedup 1.0000x reference)
//
#include <hip/hip_runtime.h>
#include <hip/hip_bf16.h>
#include <math.h>

#define N_NODES 50000
#define NEDGES  800000
#define ETOT    (NEDGES + N_NODES)   // edges + self loops
#define FIN     128
#define HID     32
#define HEADS   8
#define F1      (HEADS * HID)        // 256
#define NC      10
#define SLOPE   0.2f

__device__ __forceinline__ float leaky(float x) { return x > 0.f ? x : SLOPE * x; }
__device__ __forceinline__ float elu_f(float x) { return x > 0.f ? x : expm1f(x); }

// bf16 pack/unpack (RNE), manual to keep codegen tight
__device__ __forceinline__ unsigned short f2bf(float f) {
    unsigned int u = __float_as_uint(f);
    u = (u + 0x7fffu + ((u >> 16) & 1u)) >> 16;
    return (unsigned short)u;
}
__device__ __forceinline__ float bflo(unsigned int u) {   // low 16 bits -> float
    return __uint_as_float(u << 16);
}
__device__ __forceinline__ float bfhi(unsigned int u) {   // high 16 bits -> float
    return __uint_as_float(u & 0xffff0000u);
}

// ---------------------------------------------------------------------------
// Edge dtype detection
// ---------------------------------------------------------------------------
__global__ void k_detect(const void* ei, int* flag) {
    const long long* p = (const long long*)ei;
    long long bad = 0;
#pragma unroll
    for (int i = 0; i < 8; ++i) {
        long long v = p[i];
        bad |= (v < 0 || v >= N_NODES) ? 1 : 0;
    }
    *flag = (bad == 0);  // 1 => int64 layout, 0 => int32 layout
}

__device__ __forceinline__ int load_edge(const void* eiv, int is64, int idx) {
    if (is64) return (int)((const long long*)eiv)[idx];
    return ((const int*)eiv)[idx];
}

// ---------------------------------------------------------------------------
// CSR build: histogram of dst, exclusive scan, scatter src into col[]
// ---------------------------------------------------------------------------
__global__ void k_deg(const void* eiv, const int* __restrict__ flag,
                      int* __restrict__ deg) {
    int i = blockIdx.x * blockDim.x + threadIdx.x;
    if (i >= ETOT) return;
    int d = (i < NEDGES) ? load_edge(eiv, *flag, NEDGES + i) : (i - NEDGES);
    atomicAdd(&deg[d], 1);
}

__global__ __launch_bounds__(1024) void k_scan(const int* __restrict__ deg,
                                               int* __restrict__ rowptr) {
    __shared__ int ssum[1024];
    __shared__ int s_carry;
    int tid = threadIdx.x;
    if (tid == 0) s_carry = 0;
    __syncthreads();
    const int PER  = 8;
    const int TILE = 1024 * PER;
    for (int base = 0; base < N_NODES; base += TILE) {
        int i0 = base + tid * PER;
        int v[PER];
        int tsum = 0;
#pragma unroll
        for (int k = 0; k < PER; ++k) {
            int i = i0 + k;
            v[k] = (i < N_NODES) ? deg[i] : 0;
            tsum += v[k];
        }
        ssum[tid] = tsum;
        __syncthreads();
        for (int off = 1; off < 1024; off <<= 1) {
            int t = (tid >= off) ? ssum[tid - off] : 0;
            __syncthreads();
            ssum[tid] += t;
            __syncthreads();
        }
        int excl = s_carry + ssum[tid] - tsum;
#pragma unroll
        for (int k = 0; k < PER; ++k) {
            int i = i0 + k;
            if (i < N_NODES) rowptr[i] = excl;
            excl += v[k];
        }
        __syncthreads();
        if (tid == 0) s_carry += ssum[1023];
        __syncthreads();
    }
    if (tid == 0) rowptr[N_NODES] = s_carry;
}

__global__ void k_fill(const void* eiv, const int* __restrict__ flag,
                       const int* __restrict__ rowptr, int* __restrict__ fill,
                       int* __restrict__ col) {
    int i = blockIdx.x * blockDim.x + threadIdx.x;
    if (i >= ETOT) return;
    int s, d;
    if (i < NEDGES) {
        int is64 = *flag;
        s = load_edge(eiv, is64, i);
        d = load_edge(eiv, is64, NEDGES + i);
    } else {
        s = i - NEDGES;
        d = s;
    }
    int pos = rowptr[d] + atomicAdd(&fill[d], 1);
    col[pos] = s;
}

// ---------------------------------------------------------------------------
// Layer 1 GEMM: h1 = x @ W1 [N,128]@[128,256] + per-(node,head) alpha dots.
// 32-node tile; thread owns 2 columns (c0, c0+128) x 16 nodes -> per LDS
// broadcast read, 8 FMAs (was 4): LDS pipe no longer the bottleneck.
// W1 re-streamed once per 32 nodes (was once per 16).
// ---------------------------------------------------------------------------
__global__ __launch_bounds__(256) void k_gemm1(
    const float4* __restrict__ x4, const float* __restrict__ W1,
    const float* __restrict__ as1, const float* __restrict__ ad1,
    unsigned short* __restrict__ h1b, float* __restrict__ alpha_s,
    float* __restrict__ alpha_d) {
    __shared__ float xs[32][FIN];           // 16 KB
    int tid = threadIdx.x;
    int node0 = blockIdx.x * 32;
    for (int idx = tid; idx < 32 * 32; idx += 256) {
        int m = idx >> 5, k4 = idx & 31;
        int n = node0 + m;
        float4 v = (n < N_NODES) ? x4[(size_t)n * 32 + k4] : float4{0.f, 0.f, 0.f, 0.f};
        *(float4*)&xs[m][k4 * 4] = v;
    }
    __syncthreads();
    int c0 = tid & 127;                     // owns cols c0 and c0+128
    int mbase = (tid >> 7) * 16;            // nodes mbase..mbase+15
    float accA[16], accB[16];
#pragma unroll
    for (int m = 0; m < 16; ++m) { accA[m] = 0.f; accB[m] = 0.f; }
    for (int k = 0; k < FIN; k += 4) {
        float wa0 = W1[(k + 0) * F1 + c0];
        float wa1 = W1[(k + 1) * F1 + c0];
        float wa2 = W1[(k + 2) * F1 + c0];
        float wa3 = W1[(k + 3) * F1 + c0];
        float wb0 = W1[(k + 0) * F1 + c0 + 128];
        float wb1 = W1[(k + 1) * F1 + c0 + 128];
        float wb2 = W1[(k + 2) * F1 + c0 + 128];
        float wb3 = W1[(k + 3) * F1 + c0 + 128];
#pragma unroll
        for (int m = 0; m < 16; ++m) {
            float4 xv = *(const float4*)&xs[mbase + m][k];  // wave-broadcast
            accA[m] = fmaf(xv.x, wa0, accA[m]);
            accA[m] = fmaf(xv.y, wa1, accA[m]);
            accA[m] = fmaf(xv.z, wa2, accA[m]);
            accA[m] = fmaf(xv.w, wa3, accA[m]);
            accB[m] = fmaf(xv.x, wb0, accB[m]);
            accB[m] = fmaf(xv.y, wb1, accB[m]);
            accB[m] = fmaf(xv.z, wb2, accB[m]);
            accB[m] = fmaf(xv.w, wb3, accB[m]);
        }
    }
    // epilogue: bf16 store + per-(node,head) alpha dots via 32-lane reduce.
    // c0 in [0,128): headA = c0>>5 in 0..3 (uniform per 32-lane group),
    // c1 = c0+128: headB = headA+4. xor offsets 16..1 reduce within group.
    int headA = c0 >> 5, headB = headA + 4;
    int cc = c0 & 31;
    float aAs = as1[headA * HID + cc], aAd = ad1[headA * HID + cc];
    float aBs = as1[headB * HID + cc], aBd = ad1[headB * HID + cc];
#pragma unroll
    for (int m = 0; m < 16; ++m) {
        int n = node0 + mbase + m;
        if (n >= N_NODES) break;
        h1b[(size_t)n * F1 + c0]       = f2bf(accA[m]);
        h1b[(size_t)n * F1 + c0 + 128] = f2bf(accB[m]);
        float vsA = accA[m] * aAs, vdA = accA[m] * aAd;
        float vsB = accB[m] * aBs, vdB = accB[m] * aBd;
#pragma unroll
        for (int off = 16; off >= 1; off >>= 1) {
            vsA += __shfl_xor(vsA, off, 64);
            vdA += __shfl_xor(vdA, off, 64);
            vsB += __shfl_xor(vsB, off, 64);
            vdB += __shfl_xor(vdB, off, 64);
        }
        if (cc == 0) {
            alpha_s[n * HEADS + headA] = vsA;
            alpha_d[n * HEADS + headA] = vdA;
            alpha_s[n * HEADS + headB] = vsB;
            alpha_d[n * HEADS + headB] = vdB;
        }
    }
}

// ---------------------------------------------------------------------------
// Layer 1 aggregation: 1 wave per dst node; lane covers channels 4*lane..+3
// (uint2 = 4 bf16 per lane = 512B/row gather). exp fused; no max-pass.
// ---------------------------------------------------------------------------
__global__ __launch_bounds__(256) void k_agg1(
    const uint2* __restrict__ h1u, const float* __restrict__ a_s,
    const float* __restrict__ a_d, const int* __restrict__ rowptr,
    const int* __restrict__ col, const float4* __restrict__ b1,
    float4* __restrict__ hout) {
    int tid = threadIdx.x;
    int lane = tid & 63;
    int n = blockIdx.x * 4 + (tid >> 6);
    if (n >= N_NODES) return;
    int head = lane >> 3;
    int start = rowptr[n], end = rowptr[n + 1];
    float adv = a_d[n * HEADS + head];
    float4 acc = {0.f, 0.f, 0.f, 0.f};
    float ssum = 0.f;
    int j = start;
    for (; j + 3 < end; j += 4) {
        int s0 = col[j], s1 = col[j + 1], s2 = col[j + 2], s3 = col[j + 3];
        uint2 g0 = h1u[(size_t)s0 * 64 + lane];
        uint2 g1 = h1u[(size_t)s1 * 64 + lane];
        uint2 g2 = h1u[(size_t)s2 * 64 + lane];
        uint2 g3 = h1u[(size_t)s3 * 64 + lane];
        float w0 = expf(leaky(a_s[s0 * HEADS + head] + adv));
        float w1 = expf(leaky(a_s[s1 * HEADS + head] + adv));
        float w2 = expf(leaky(a_s[s2 * HEADS + head] + adv));
        float w3 = expf(leaky(a_s[s3 * HEADS + head] + adv));
        acc.x = fmaf(w0, bflo(g0.x), acc.x); acc.y = fmaf(w0, bfhi(g0.x), acc.y);
        acc.z = fmaf(w0, bflo(g0.y), acc.z); acc.w = fmaf(w0, bfhi(g0.y), acc.w);
        acc.x = fmaf(w1, bflo(g1.x), acc.x); acc.y = fmaf(w1, bfhi(g1.x), acc.y);
        acc.z = fmaf(w1, bflo(g1.y), acc.z); acc.w = fmaf(w1, bfhi(g1.y), acc.w);
        acc.x = fmaf(w2, bflo(g2.x), acc.x); acc.y = fmaf(w2, bfhi(g2.x), acc.y);
        acc.z = fmaf(w2, bflo(g2.y), acc.z); acc.w = fmaf(w2, bfhi(g2.y), acc.w);
        acc.x = fmaf(w3, bflo(g3.x), acc.x); acc.y = fmaf(w3, bfhi(g3.x), acc.y);
        acc.z = fmaf(w3, bflo(g3.y), acc.z); acc.w = fmaf(w3, bfhi(g3.y), acc.w);
        ssum += (w0 + w1) + (w2 + w3);
    }
    for (; j < end; ++j) {
        int s0 = col[j];
        uint2 g0 = h1u[(size_t)s0 * 64 + lane];
        float w0 = expf(leaky(a_s[s0 * HEADS + head] + adv));
        acc.x = fmaf(w0, bflo(g0.x), acc.x); acc.y = fmaf(w0, bfhi(g0.x), acc.y);
        acc.z = fmaf(w0, bflo(g0.y), acc.z); acc.w = fmaf(w0, bfhi(g0.y), acc.w);
        ssum += w0;
    }
    float inv = 1.f / ssum;
    float4 b = b1[lane];
    float4 o;
    o.x = elu_f(fmaf(acc.x, inv, b.x));
    o.y = elu_f(fmaf(acc.y, inv, b.y));
    o.z = elu_f(fmaf(acc.z, inv, b.z));
    o.w = elu_f(fmaf(acc.w, inv, b.w));
    hout[(size_t)n * 64 + lane] = o;
}

// ---------------------------------------------------------------------------
// Layer 2 GEMM: h2 = hin @ W2 [N,256]@[256,32] + alpha scalars.
// Thread owns 2 columns (c, c+16) x 1 node -> 1 ds_read per 8 FMAs.
// LDS padded [16][260] to break the 4-rows-same-bank aliasing.
// ---------------------------------------------------------------------------
__global__ __launch_bounds__(256) void k_gemm2(
    const float4* __restrict__ hin4, const float* __restrict__ W2,
    const float* __restrict__ as2, const float* __restrict__ ad2,
    float* __restrict__ h2, float* __restrict__ alpha_s, float* __restrict__ alpha_d) {
    __shared__ float hs[16][F1 + 4];
    int tid = threadIdx.x;
    int node0 = blockIdx.x * 16;
    for (int idx = tid; idx < 16 * 64; idx += 256) {
        int m = idx >> 6, k4 = idx & 63;
        int n = node0 + m;
        float4 v = (n < N_NODES) ? hin4[(size_t)n * 64 + k4] : float4{0.f, 0.f, 0.f, 0.f};
        *(float4*)&hs[m][k4 * 4] = v;
    }
    __syncthreads();
    int c = tid & 15;            // cols c and c+16
    int m = tid >> 4;            // node 0..15
    float acc0 = 0.f, acc1 = 0.f;
    for (int k = 0; k < F1; k += 4) {
        float w00 = W2[(k + 0) * HID + c];
        float w01 = W2[(k + 1) * HID + c];
        float w02 = W2[(k + 2) * HID + c];
        float w03 = W2[(k + 3) * HID + c];
        float w10 = W2[(k + 0) * HID + c + 16];
        float w11 = W2[(k + 1) * HID + c + 16];
        float w12 = W2[(k + 2) * HID + c + 16];
        float w13 = W2[(k + 3) * HID + c + 16];
        float4 xv = *(const float4*)&hs[m][k];
        acc0 = fmaf(xv.w, w03, fmaf(xv.z, w02, fmaf(xv.y, w01, fmaf(xv.x, w00, acc0))));
        acc1 = fmaf(xv.w, w13, fmaf(xv.z, w12, fmaf(xv.y, w11, fmaf(xv.x, w10, acc1))));
    }
    int n = node0 + m;
    if (n < N_NODES) {
        h2[(size_t)n * HID + c]      = acc0;
        h2[(size_t)n * HID + c + 16] = acc1;
        float vs = acc0 * as2[c] + acc1 * as2[c + 16];
        float vd = acc0 * ad2[c] + acc1 * ad2[c + 16];
#pragma unroll
        for (int off = 8; off >= 1; off >>= 1) {   // reduce 16-lane group (same node)
            vs += __shfl_xor(vs, off, 64);
            vd += __shfl_xor(vd, off, 64);
        }
        if (c == 0) {
            alpha_s[n] = vs;
            alpha_d[n] = vd;
        }
    }
}

// ---------------------------------------------------------------------------
// Layer 2 aggregation: 8 nodes/block (32 ch each), exp fused inline.
// ---------------------------------------------------------------------------
__global__ __launch_bounds__(256) void k_agg2(
    const float* __restrict__ h2, const float* __restrict__ a_s,
    const float* __restrict__ a_d, const int* __restrict__ rowptr,
    const int* __restrict__ col, const float* __restrict__ b2,
    float* __restrict__ hout) {
    int tid = threadIdx.x;
    int ml = tid >> 5, c = tid & 31;
    int n = blockIdx.x * 8 + ml;
    if (n >= N_NODES) return;
    int start = rowptr[n], end = rowptr[n + 1];
    float adv = a_d[n];
    float ssum = 0.f, acc = 0.f;
    int j = start;
    for (; j + 1 < end; j += 2) {
        int s0 = col[j], s1 = col[j + 1];
        float v0 = h2[(size_t)s0 * HID + c];
        float v1 = h2[(size_t)s1 * HID + c];
        float w0 = expf(leaky(a_s[s0] + adv));
        float w1 = expf(leaky(a_s[s1] + adv));
        acc = fmaf(w0, v0, acc);
        acc = fmaf(w1, v1, acc);
        ssum += w0 + w1;
    }
    if (j < end) {
        int s0 = col[j];
        float w0 = expf(leaky(a_s[s0] + adv));
        acc = fmaf(w0, h2[(size_t)s0 * HID + c], acc);
        ssum += w0;
    }
    hout[(size_t)n * HID + c] = elu_f(acc / ssum + b2[c]);
}

// ---------------------------------------------------------------------------
// Final linear: out = h2f @ Wl + bl [N,32]@[32,10]
// ---------------------------------------------------------------------------
__global__ void k_final(const float* __restrict__ hf, const float* __restrict__ Wl,
                        const float* __restrict__ bl, float* __restrict__ out) {
    int n = blockIdx.x * blockDim.x + threadIdx.x;
    if (n >= N_NODES) return;
    float h[HID];
    const float4* hp = (const float4*)(hf + (size_t)n * HID);
#pragma unroll
    for (int i = 0; i < 8; ++i) {
        float4 v = hp[i];
        h[4 * i] = v.x; h[4 * i + 1] = v.y; h[4 * i + 2] = v.z; h[4 * i + 3] = v.w;
    }
#pragma unroll
    for (int j = 0; j < NC; ++j) {
        float acc = bl[j];
#pragma unroll
        for (int c = 0; c < HID; ++c) acc += h[c] * Wl[c * NC + j];
        out[(size_t)n * NC + j] = acc;
    }
}

// ---------------------------------------------------------------------------
extern "C" void kernel_launch(void* const* d_in, const int* in_sizes, int n_in,
                              void* d_out, int out_size, void* d_ws, size_t ws_size,
                              hipStream_t stream) {
    (void)in_sizes; (void)n_in; (void)out_size; (void)ws_size;
    const float* x   = (const float*)d_in[0];
    const void*  ei  = d_in[1];
    const float* W1  = (const float*)d_in[2];
    const float* as1 = (const float*)d_in[3];
    const float* ad1 = (const float*)d_in[4];
    const float* b1  = (const float*)d_in[5];
    const float* W2  = (const float*)d_in[6];
    const float* as2 = (const float*)d_in[7];
    const float* ad2 = (const float*)d_in[8];
    const float* b2  = (const float*)d_in[9];
    const float* Wl  = (const float*)d_in[10];
    const float* bl  = (const float*)d_in[11];
    float* out = (float*)d_out;

    char* ws = (char*)d_ws;
    size_t off = 0;
    auto alloc = [&](size_t bytes) {
        void* p = ws + off;
        off += (bytes + 255) & ~size_t(255);
        return p;
    };
    int*   flag    = (int*)alloc(4);
    int*   deg     = (int*)alloc(N_NODES * 4);
    int*   fill    = (int*)alloc(N_NODES * 4);
    int*   rowptr  = (int*)alloc((N_NODES + 1) * 4);
    int*   col     = (int*)alloc(ETOT * 4);
    unsigned short* h1b = (unsigned short*)alloc((size_t)N_NODES * F1 * 2);  // bf16
    float* as1n    = (float*)alloc(N_NODES * HEADS * 4);
    float* ad1n    = (float*)alloc(N_NODES * HEADS * 4);
    float* hin2    = (float*)alloc((size_t)N_NODES * F1 * 4);
    float* h2      = (float*)alloc((size_t)N_NODES * HID * 4);
    float* as2n    = (float*)alloc(N_NODES * 4);
    float* ad2n    = (float*)alloc(N_NODES * 4);
    // h1b dead after k_agg1; h2f written later in k_agg2 -> safe alias
    float* h2f     = (float*)h1b;   // needs N*HID*4 = 6.4MB <= 25.6MB

    hipMemsetAsync(deg, 0, N_NODES * 4, stream);
    hipMemsetAsync(fill, 0, N_NODES * 4, stream);

    k_detect<<<1, 1, 0, stream>>>(ei, flag);

    int egrid = (ETOT + 255) / 256;
    k_deg<<<egrid, 256, 0, stream>>>(ei, flag, deg);
    k_scan<<<1, 1024, 0, stream>>>(deg, rowptr);
    k_fill<<<egrid, 256, 0, stream>>>(ei, flag, rowptr, fill, col);

    k_gemm1<<<(N_NODES + 31) / 32, 256, 0, stream>>>((const float4*)x, W1, as1, ad1,
                                                     h1b, as1n, ad1n);
    k_agg1<<<(N_NODES + 3) / 4, 256, 0, stream>>>((const uint2*)h1b, as1n, ad1n, rowptr,
                                                  col, (const float4*)b1, (float4*)hin2);
    k_gemm2<<<(N_NODES + 15) / 16, 256, 0, stream>>>((const float4*)hin2, W2, as2, ad2,
                                                     h2, as2n, ad2n);
    k_agg2<<<(N_NODES + 7) / 8, 256, 0, stream>>>(h2, as2n, ad2n, rowptr, col, b2, h2f);
    k_final<<<(N_NODES + 255) / 256, 256, 0, stream>>>(h2f, Wl, bl, out);
}

// Round 14
// 423.540 us; speedup vs baseline: 1.0282x; 1.0282x over previous
//
#include <hip/hip_runtime.h>
#include <hip/hip_bf16.h>
#include <math.h>

#define N_NODES 50000
#define NEDGES  800000
#define ETOT    (NEDGES + N_NODES)   // edges + self loops
#define FIN     128
#define HID     32
#define HEADS   8
#define F1      (HEADS * HID)        // 256
#define NC      10
#define SLOPE   0.2f
#define SCB     49                   // ceil(50000/1024) scan blocks

__device__ __forceinline__ float leaky(float x) { return x > 0.f ? x : SLOPE * x; }
__device__ __forceinline__ float elu_f(float x) { return x > 0.f ? x : expm1f(x); }

// bf16 pack/unpack (RNE)
__device__ __forceinline__ unsigned short f2bf(float f) {
    unsigned int u = __float_as_uint(f);
    u = (u + 0x7fffu + ((u >> 16) & 1u)) >> 16;
    return (unsigned short)u;
}
__device__ __forceinline__ float bflo(unsigned int u) { return __uint_as_float(u << 16); }
__device__ __forceinline__ float bfhi(unsigned int u) { return __uint_as_float(u & 0xffff0000u); }

// ---------------------------------------------------------------------------
// Edge dtype detection
// ---------------------------------------------------------------------------
__global__ void k_detect(const void* ei, int* flag) {
    const long long* p = (const long long*)ei;
    long long bad = 0;
#pragma unroll
    for (int i = 0; i < 8; ++i) {
        long long v = p[i];
        bad |= (v < 0 || v >= N_NODES) ? 1 : 0;
    }
    *flag = (bad == 0);
}

__device__ __forceinline__ int load_edge(const void* eiv, int is64, int idx) {
    if (is64) return (int)((const long long*)eiv)[idx];
    return ((const int*)eiv)[idx];
}

// ---------------------------------------------------------------------------
// CSR build: histogram, PARALLEL 3-phase scan, scatter
// ---------------------------------------------------------------------------
__global__ void k_deg(const void* eiv, const int* __restrict__ flag,
                      int* __restrict__ deg) {
    int i = blockIdx.x * blockDim.x + threadIdx.x;
    if (i >= ETOT) return;
    int d = (i < NEDGES) ? load_edge(eiv, *flag, NEDGES + i) : (i - NEDGES);
    atomicAdd(&deg[d], 1);
}

// phase A: per-1024-chunk sums (49 blocks x 256 thr x 4 elems)
__global__ __launch_bounds__(256) void k_scan_a(const int* __restrict__ deg,
                                                int* __restrict__ bsum) {
    int b = blockIdx.x, t = threadIdx.x;
    int base = b * 1024 + t * 4;
    int s = 0;
#pragma unroll
    for (int i = 0; i < 4; ++i) {
        int idx = base + i;
        s += (idx < N_NODES) ? deg[idx] : 0;
    }
#pragma unroll
    for (int off = 32; off >= 1; off >>= 1) s += __shfl_xor(s, off, 64);
    __shared__ int ws[4];
    int lane = t & 63, w = t >> 6;
    if (lane == 0) ws[w] = s;
    __syncthreads();
    if (t == 0) bsum[b] = ws[0] + ws[1] + ws[2] + ws[3];
}

// phase B: 1 wave scans the 49 chunk sums; writes rowptr[N_NODES]=total
__global__ void k_scan_b(const int* __restrict__ bsum, int* __restrict__ boff,
                         int* __restrict__ rowptr) {
    int lane = threadIdx.x;   // blockDim = 64
    int v = (lane < SCB) ? bsum[lane] : 0;
    int inc = v;
#pragma unroll
    for (int off = 1; off < 64; off <<= 1) {
        int up = __shfl_up(inc, off, 64);
        if (lane >= off) inc += up;
    }
    if (lane < SCB) boff[lane] = inc - v;
    if (lane == 63) rowptr[N_NODES] = inc;
}

// phase C: per-chunk rescan with global offset -> rowptr
__global__ __launch_bounds__(256) void k_scan_c(const int* __restrict__ deg,
                                                const int* __restrict__ boff,
                                                int* __restrict__ rowptr) {
    int b = blockIdx.x, t = threadIdx.x;
    int base = b * 1024 + t * 4;
    int v[4];
    int ts = 0;
#pragma unroll
    for (int i = 0; i < 4; ++i) {
        int idx = base + i;
        v[i] = (idx < N_NODES) ? deg[idx] : 0;
        ts += v[i];
    }
    int inc = ts;
#pragma unroll
    for (int off = 1; off < 64; off <<= 1) {
        int up = __shfl_up(inc, off, 64);
        if ((t & 63) >= off) inc += up;
    }
    __shared__ int ws[4];
    int lane = t & 63, w = t >> 6;
    if (lane == 63) ws[w] = inc;
    __syncthreads();
    int woff = 0;
    for (int i = 0; i < w; ++i) woff += ws[i];
    int excl = boff[b] + woff + inc - ts;
#pragma unroll
    for (int i = 0; i < 4; ++i) {
        int idx = base + i;
        if (idx < N_NODES) rowptr[idx] = excl;
        excl += v[i];
    }
}

__global__ void k_fill(const void* eiv, const int* __restrict__ flag,
                       const int* __restrict__ rowptr, int* __restrict__ fill,
                       int* __restrict__ col) {
    int i = blockIdx.x * blockDim.x + threadIdx.x;
    if (i >= ETOT) return;
    int s, d;
    if (i < NEDGES) {
        int is64 = *flag;
        s = load_edge(eiv, is64, i);
        d = load_edge(eiv, is64, NEDGES + i);
    } else {
        s = i - NEDGES;
        d = s;
    }
    int pos = rowptr[d] + atomicAdd(&fill[d], 1);
    col[pos] = s;
}

// ---------------------------------------------------------------------------
// Layer 1 GEMM with explicit W1 double-buffer prefetch: load k-group g+1 into
// regs BEFORE the 128-FMA block for group g, so L2 latency hides under VALU.
// ---------------------------------------------------------------------------
__global__ __launch_bounds__(256) void k_gemm1(
    const float4* __restrict__ x4, const float* __restrict__ W1,
    const float* __restrict__ as1, const float* __restrict__ ad1,
    unsigned short* __restrict__ h1b, float* __restrict__ alpha_s,
    float* __restrict__ alpha_d) {
    __shared__ float xs[32][FIN];           // 16 KB
    int tid = threadIdx.x;
    int node0 = blockIdx.x * 32;
    for (int idx = tid; idx < 32 * 32; idx += 256) {
        int m = idx >> 5, k4 = idx & 31;
        int n = node0 + m;
        float4 v = (n < N_NODES) ? x4[(size_t)n * 32 + k4] : float4{0.f, 0.f, 0.f, 0.f};
        *(float4*)&xs[m][k4 * 4] = v;
    }
    __syncthreads();
    int c0 = tid & 127;
    int mbase = (tid >> 7) * 16;
    float accA[16], accB[16];
#pragma unroll
    for (int m = 0; m < 16; ++m) { accA[m] = 0.f; accB[m] = 0.f; }

#define LOADW(A, B, KK)                                   \
    {                                                     \
        const float* _p = W1 + (KK) * F1 + c0;            \
        A[0] = _p[0 * F1]; A[1] = _p[1 * F1];             \
        A[2] = _p[2 * F1]; A[3] = _p[3 * F1];             \
        B[0] = _p[0 * F1 + 128]; B[1] = _p[1 * F1 + 128]; \
        B[2] = _p[2 * F1 + 128]; B[3] = _p[3 * F1 + 128]; \
    }
#define FMAS(KK, A, B)                                                \
    _Pragma("unroll") for (int m = 0; m < 16; ++m) {                  \
        float4 xv = *(const float4*)&xs[mbase + m][KK];               \
        accA[m] = fmaf(xv.x, A[0], accA[m]);                          \
        accA[m] = fmaf(xv.y, A[1], accA[m]);                          \
        accA[m] = fmaf(xv.z, A[2], accA[m]);                          \
        accA[m] = fmaf(xv.w, A[3], accA[m]);                          \
        accB[m] = fmaf(xv.x, B[0], accB[m]);                          \
        accB[m] = fmaf(xv.y, B[1], accB[m]);                          \
        accB[m] = fmaf(xv.z, B[2], accB[m]);                          \
        accB[m] = fmaf(xv.w, B[3], accB[m]);                          \
    }

    float ca[4], cb[4];
    LOADW(ca, cb, 0);
    for (int k = 0; k < FIN - 4; k += 4) {
        float na[4], nb[4];
        LOADW(na, nb, k + 4);       // prefetch next group
        FMAS(k, ca, cb);            // consume current group
#pragma unroll
        for (int j = 0; j < 4; ++j) { ca[j] = na[j]; cb[j] = nb[j]; }
    }
    FMAS(FIN - 4, ca, cb);
#undef LOADW
#undef FMAS

    int headA = c0 >> 5, headB = headA + 4;
    int cc = c0 & 31;
    float aAs = as1[headA * HID + cc], aAd = ad1[headA * HID + cc];
    float aBs = as1[headB * HID + cc], aBd = ad1[headB * HID + cc];
#pragma unroll
    for (int m = 0; m < 16; ++m) {
        int n = node0 + mbase + m;
        if (n >= N_NODES) break;
        h1b[(size_t)n * F1 + c0]       = f2bf(accA[m]);
        h1b[(size_t)n * F1 + c0 + 128] = f2bf(accB[m]);
        float vsA = accA[m] * aAs, vdA = accA[m] * aAd;
        float vsB = accB[m] * aBs, vdB = accB[m] * aBd;
#pragma unroll
        for (int off = 16; off >= 1; off >>= 1) {
            vsA += __shfl_xor(vsA, off, 64);
            vdA += __shfl_xor(vdA, off, 64);
            vsB += __shfl_xor(vsB, off, 64);
            vdB += __shfl_xor(vdB, off, 64);
        }
        if (cc == 0) {
            alpha_s[n * HEADS + headA] = vsA;
            alpha_d[n * HEADS + headA] = vdA;
            alpha_s[n * HEADS + headB] = vsB;
            alpha_d[n * HEADS + headB] = vdB;
        }
    }
}

// ---------------------------------------------------------------------------
// Layer 1 aggregation (unchanged): 1 wave per dst node, bf16 uint2 gather,
// exp fused inline (no max-pass).
// ---------------------------------------------------------------------------
__global__ __launch_bounds__(256) void k_agg1(
    const uint2* __restrict__ h1u, const float* __restrict__ a_s,
    const float* __restrict__ a_d, const int* __restrict__ rowptr,
    const int* __restrict__ col, const float4* __restrict__ b1,
    float4* __restrict__ hout) {
    int tid = threadIdx.x;
    int lane = tid & 63;
    int n = blockIdx.x * 4 + (tid >> 6);
    if (n >= N_NODES) return;
    int head = lane >> 3;
    int start = rowptr[n], end = rowptr[n + 1];
    float adv = a_d[n * HEADS + head];
    float4 acc = {0.f, 0.f, 0.f, 0.f};
    float ssum = 0.f;
    int j = start;
    for (; j + 3 < end; j += 4) {
        int s0 = col[j], s1 = col[j + 1], s2 = col[j + 2], s3 = col[j + 3];
        uint2 g0 = h1u[(size_t)s0 * 64 + lane];
        uint2 g1 = h1u[(size_t)s1 * 64 + lane];
        uint2 g2 = h1u[(size_t)s2 * 64 + lane];
        uint2 g3 = h1u[(size_t)s3 * 64 + lane];
        float w0 = expf(leaky(a_s[s0 * HEADS + head] + adv));
        float w1 = expf(leaky(a_s[s1 * HEADS + head] + adv));
        float w2 = expf(leaky(a_s[s2 * HEADS + head] + adv));
        float w3 = expf(leaky(a_s[s3 * HEADS + head] + adv));
        acc.x = fmaf(w0, bflo(g0.x), acc.x); acc.y = fmaf(w0, bfhi(g0.x), acc.y);
        acc.z = fmaf(w0, bflo(g0.y), acc.z); acc.w = fmaf(w0, bfhi(g0.y), acc.w);
        acc.x = fmaf(w1, bflo(g1.x), acc.x); acc.y = fmaf(w1, bfhi(g1.x), acc.y);
        acc.z = fmaf(w1, bflo(g1.y), acc.z); acc.w = fmaf(w1, bfhi(g1.y), acc.w);
        acc.x = fmaf(w2, bflo(g2.x), acc.x); acc.y = fmaf(w2, bfhi(g2.x), acc.y);
        acc.z = fmaf(w2, bflo(g2.y), acc.z); acc.w = fmaf(w2, bfhi(g2.y), acc.w);
        acc.x = fmaf(w3, bflo(g3.x), acc.x); acc.y = fmaf(w3, bfhi(g3.x), acc.y);
        acc.z = fmaf(w3, bflo(g3.y), acc.z); acc.w = fmaf(w3, bfhi(g3.y), acc.w);
        ssum += (w0 + w1) + (w2 + w3);
    }
    for (; j < end; ++j) {
        int s0 = col[j];
        uint2 g0 = h1u[(size_t)s0 * 64 + lane];
        float w0 = expf(leaky(a_s[s0 * HEADS + head] + adv));
        acc.x = fmaf(w0, bflo(g0.x), acc.x); acc.y = fmaf(w0, bfhi(g0.x), acc.y);
        acc.z = fmaf(w0, bflo(g0.y), acc.z); acc.w = fmaf(w0, bfhi(g0.y), acc.w);
        ssum += w0;
    }
    float inv = 1.f / ssum;
    float4 b = b1[lane];
    float4 o;
    o.x = elu_f(fmaf(acc.x, inv, b.x));
    o.y = elu_f(fmaf(acc.y, inv, b.y));
    o.z = elu_f(fmaf(acc.z, inv, b.z));
    o.w = elu_f(fmaf(acc.w, inv, b.w));
    hout[(size_t)n * 64 + lane] = o;
}

// ---------------------------------------------------------------------------
// Layer 2 GEMM (unchanged from R10): 2 cols/thread, padded LDS.
// ---------------------------------------------------------------------------
__global__ __launch_bounds__(256) void k_gemm2(
    const float4* __restrict__ hin4, const float* __restrict__ W2,
    const float* __restrict__ as2, const float* __restrict__ ad2,
    float* __restrict__ h2, float* __restrict__ alpha_s, float* __restrict__ alpha_d) {
    __shared__ float hs[16][F1 + 4];
    int tid = threadIdx.x;
    int node0 = blockIdx.x * 16;
    for (int idx = tid; idx < 16 * 64; idx += 256) {
        int m = idx >> 6, k4 = idx & 63;
        int n = node0 + m;
        float4 v = (n < N_NODES) ? hin4[(size_t)n * 64 + k4] : float4{0.f, 0.f, 0.f, 0.f};
        *(float4*)&hs[m][k4 * 4] = v;
    }
    __syncthreads();
    int c = tid & 15;
    int m = tid >> 4;
    float acc0 = 0.f, acc1 = 0.f;
    for (int k = 0; k < F1; k += 4) {
        float w00 = W2[(k + 0) * HID + c];
        float w01 = W2[(k + 1) * HID + c];
        float w02 = W2[(k + 2) * HID + c];
        float w03 = W2[(k + 3) * HID + c];
        float w10 = W2[(k + 0) * HID + c + 16];
        float w11 = W2[(k + 1) * HID + c + 16];
        float w12 = W2[(k + 2) * HID + c + 16];
        float w13 = W2[(k + 3) * HID + c + 16];
        float4 xv = *(const float4*)&hs[m][k];
        acc0 = fmaf(xv.w, w03, fmaf(xv.z, w02, fmaf(xv.y, w01, fmaf(xv.x, w00, acc0))));
        acc1 = fmaf(xv.w, w13, fmaf(xv.z, w12, fmaf(xv.y, w11, fmaf(xv.x, w10, acc1))));
    }
    int n = node0 + m;
    if (n < N_NODES) {
        h2[(size_t)n * HID + c]      = acc0;
        h2[(size_t)n * HID + c + 16] = acc1;
        float vs = acc0 * as2[c] + acc1 * as2[c + 16];
        float vd = acc0 * ad2[c] + acc1 * ad2[c + 16];
#pragma unroll
        for (int off = 8; off >= 1; off >>= 1) {
            vs += __shfl_xor(vs, off, 64);
            vd += __shfl_xor(vd, off, 64);
        }
        if (c == 0) {
            alpha_s[n] = vs;
            alpha_d[n] = vd;
        }
    }
}

// ---------------------------------------------------------------------------
// Layer 2 aggregation + FUSED final linear: 8 nodes/block, ELU result goes to
// LDS, then 80 threads compute out = h2f @ Wl + bl directly. Grid = 6250
// exactly (50000/8) so every thread has a valid node -> barrier-safe.
// ---------------------------------------------------------------------------
__global__ __launch_bounds__(256) void k_agg2(
    const float* __restrict__ h2, const float* __restrict__ a_s,
    const float* __restrict__ a_d, const int* __restrict__ rowptr,
    const int* __restrict__ col, const float* __restrict__ b2,
    const float* __restrict__ Wl, const float* __restrict__ bl,
    float* __restrict__ out) {
    __shared__ float sh[8][HID];
    int tid = threadIdx.x;
    int ml = tid >> 5, c = tid & 31;
    int n = blockIdx.x * 8 + ml;   // always < N_NODES (6250*8 == 50000)
    int start = rowptr[n], end = rowptr[n + 1];
    float adv = a_d[n];
    float ssum = 0.f, acc = 0.f;
    int j = start;
    for (; j + 1 < end; j += 2) {
        int s0 = col[j], s1 = col[j + 1];
        float v0 = h2[(size_t)s0 * HID + c];
        float v1 = h2[(size_t)s1 * HID + c];
        float w0 = expf(leaky(a_s[s0] + adv));
        float w1 = expf(leaky(a_s[s1] + adv));
        acc = fmaf(w0, v0, acc);
        acc = fmaf(w1, v1, acc);
        ssum += w0 + w1;
    }
    if (j < end) {
        int s0 = col[j];
        float w0 = expf(leaky(a_s[s0] + adv));
        acc = fmaf(w0, h2[(size_t)s0 * HID + c], acc);
        ssum += w0;
    }
    sh[ml][c] = elu_f(acc / ssum + b2[c]);
    __syncthreads();
    if (tid < 8 * NC) {
        int nl = tid / NC, jj = tid - nl * NC;
        float o = bl[jj];
#pragma unroll
        for (int cc = 0; cc < HID; ++cc)
            o = fmaf(sh[nl][cc], Wl[cc * NC + jj], o);
        out[(size_t)(blockIdx.x * 8 + nl) * NC + jj] = o;
    }
}

// ---------------------------------------------------------------------------
extern "C" void kernel_launch(void* const* d_in, const int* in_sizes, int n_in,
                              void* d_out, int out_size, void* d_ws, size_t ws_size,
                              hipStream_t stream) {
    (void)in_sizes; (void)n_in; (void)out_size; (void)ws_size;
    const float* x   = (const float*)d_in[0];
    const void*  ei  = d_in[1];
    const float* W1  = (const float*)d_in[2];
    const float* as1 = (const float*)d_in[3];
    const float* ad1 = (const float*)d_in[4];
    const float* b1  = (const float*)d_in[5];
    const float* W2  = (const float*)d_in[6];
    const float* as2 = (const float*)d_in[7];
    const float* ad2 = (const float*)d_in[8];
    const float* b2  = (const float*)d_in[9];
    const float* Wl  = (const float*)d_in[10];
    const float* bl  = (const float*)d_in[11];
    float* out = (float*)d_out;

    char* ws = (char*)d_ws;
    size_t off = 0;
    auto alloc = [&](size_t bytes) {
        void* p = ws + off;
        off += (bytes + 255) & ~size_t(255);
        return p;
    };
    int*   flag    = (int*)alloc(4);
    int*   deg     = (int*)alloc(N_NODES * 4);
    int*   fill    = (int*)alloc(N_NODES * 4);
    int*   rowptr  = (int*)alloc((N_NODES + 1) * 4);
    int*   bsum    = (int*)alloc(SCB * 4);
    int*   boff    = (int*)alloc(SCB * 4);
    int*   col     = (int*)alloc(ETOT * 4);
    unsigned short* h1b = (unsigned short*)alloc((size_t)N_NODES * F1 * 2);  // bf16
    float* as1n    = (float*)alloc(N_NODES * HEADS * 4);
    float* ad1n    = (float*)alloc(N_NODES * HEADS * 4);
    float* hin2    = (float*)alloc((size_t)N_NODES * F1 * 4);
    float* h2      = (float*)alloc((size_t)N_NODES * HID * 4);
    float* as2n    = (float*)alloc(N_NODES * 4);
    float* ad2n    = (float*)alloc(N_NODES * 4);

    hipMemsetAsync(deg, 0, N_NODES * 4, stream);
    hipMemsetAsync(fill, 0, N_NODES * 4, stream);

    k_detect<<<1, 1, 0, stream>>>(ei, flag);

    int egrid = (ETOT + 255) / 256;
    k_deg<<<egrid, 256, 0, stream>>>(ei, flag, deg);
    k_scan_a<<<SCB, 256, 0, stream>>>(deg, bsum);
    k_scan_b<<<1, 64, 0, stream>>>(bsum, boff, rowptr);
    k_scan_c<<<SCB, 256, 0, stream>>>(deg, boff, rowptr);
    k_fill<<<egrid, 256, 0, stream>>>(ei, flag, rowptr, fill, col);

    k_gemm1<<<(N_NODES + 31) / 32, 256, 0, stream>>>((const float4*)x, W1, as1, ad1,
                                                     h1b, as1n, ad1n);
    k_agg1<<<(N_NODES + 3) / 4, 256, 0, stream>>>((const uint2*)h1b, as1n, ad1n, rowptr,
                                                  col, (const float4*)b1, (float4*)hin2);
    k_gemm2<<<(N_NODES + 15) / 16, 256, 0, stream>>>((const float4*)hin2, W2, as2, ad2,
                                                     h2, as2n, ad2n);
    k_agg2<<<N_NODES / 8, 256, 0, stream>>>(h2, as2n, ad2n, rowptr, col, b2,
                                            Wl, bl, out);
}